// Round 3
// baseline (9020.027 us; speedup 1.0000x reference)
//
#include <hip/hip_runtime.h>
#include <hip/hip_bf16.h>
#include <cstdint>

using bf16 = __hip_bfloat16;

static constexpr int B = 2;
static constexpr int N = 2048;
static constexpr int KNN = 32;
static constexpr int FD = 480;
static constexpr float EPS = 1e-5f;
static constexpr float SLOPE = 0.2f;

__device__ __forceinline__ float lrelu(float x) { return x >= 0.f ? x : SLOPE * x; }

// ---------------------------------------------------------------- dtype sniff
// Read buffer as bf16. fp32 data seen this way contains huge garbage values
// (random mantissa halves); bf16 N(0,1) data maxes ~5. flag=1 -> fp32.
__global__ void sniff_kernel(const unsigned short* __restrict__ xr, int nelem,
                             int* __restrict__ flag) {
  __shared__ float red[256];
  float mx = 0.f;
  for (int i = threadIdx.x; i < nelem; i += 256) {
    float v = __uint_as_float(((unsigned)xr[i]) << 16);
    v = fabsf(v);
    if (!(v < 1e30f)) v = 1e30f;  // NaN/inf -> huge
    mx = fmaxf(mx, v);
  }
  red[threadIdx.x] = mx;
  __syncthreads();
  for (int s = 128; s > 0; s >>= 1) {
    if (threadIdx.x < s) red[threadIdx.x] = fmaxf(red[threadIdx.x], red[threadIdx.x + s]);
    __syncthreads();
  }
  if (threadIdx.x == 0) flag[0] = (red[0] > 1e3f) ? 1 : 0;
}

__device__ __forceinline__ float load_in(const void* p, int i, int isf32) {
  return isf32 ? ((const float*)p)[i] : __bfloat162float(((const bf16*)p)[i]);
}

// ---------------------------------------------------------------- prep
__global__ void convert_kernel(const void* __restrict__ x, float* __restrict__ xf, int n,
                               const int* __restrict__ flag) {
  int i = blockIdx.x * 256 + threadIdx.x;
  int isf = flag[0];
  if (i < n) xf[i] = load_in(x, i, isf);
}

// W [O][IC] -> Wt [IC][O] (fp32)
__global__ void transpose_w_kernel(const void* __restrict__ W, float* __restrict__ Wt,
                                   int O, int IC, const int* __restrict__ flag) {
  int i = blockIdx.x * 256 + threadIdx.x;
  int isf = flag[0];
  if (i < O * IC) {
    int o = i / IC, c = i - o * IC;
    Wt[c * O + o] = load_in(W, i, isf);
  }
}

// ---------------------------------------------------------------- knn
__global__ void sq_kernel(const float* __restrict__ h, int stride, int C,
                          float* __restrict__ sqv) {
  int i = blockIdx.x * 256 + threadIdx.x;  // b*N + n
  const float* r = h + (size_t)i * stride;
  float s = 0.f;
  for (int c = 0; c < C; ++c) s += r[c] * r[c];
  sqv[i] = s;
}

// Fused distance + top-33 selection. One block = 64 rows of one batch,
// scans all 2048 columns in 64-wide tiles. No global distance matrix.
template <int C>
__global__ __launch_bounds__(256) void knn_kernel(const float* __restrict__ h, int hstride,
                                                  const float* __restrict__ sqv,
                                                  int* __restrict__ idxb) {
  constexpr int CW = 32;
  __shared__ float As[64][CW + 1];
  __shared__ float Bs[64][CW + 1];
  __shared__ float dtile[64][65];
  __shared__ unsigned long long top[64][KNN + 1];  // sorted ascending, 33 entries

  int b = blockIdx.y;
  int n0 = blockIdx.x * 64;
  int tid = threadIdx.x;
  int tx = tid & 15, ty = tid >> 4;

  for (int i = tid; i < 64 * (KNN + 1); i += 256)
    (&top[0][0])[i] = ~0ull;
  __syncthreads();

  for (int mt = 0; mt < N / 64; ++mt) {
    int m0 = mt * 64;
    float dot[4][4] = {};
    for (int cc = 0; cc < C; cc += CW) {
      for (int i = tid; i < 64 * CW; i += 256) {
        int r = i >> 5, c = i & 31;
        int gc = cc + c;
        float av = 0.f, bv = 0.f;
        if (gc < C) {
          av = h[(size_t)(b * N + n0 + r) * hstride + gc];
          bv = h[(size_t)(b * N + m0 + r) * hstride + gc];
        }
        As[r][c] = av;
        Bs[r][c] = bv;
      }
      __syncthreads();
      for (int c = 0; c < CW; ++c) {
        float av[4], bv[4];
#pragma unroll
        for (int i = 0; i < 4; ++i) av[i] = As[ty * 4 + i][c];
#pragma unroll
        for (int j = 0; j < 4; ++j) bv[j] = Bs[tx * 4 + j][c];
#pragma unroll
        for (int i = 0; i < 4; ++i)
#pragma unroll
          for (int j = 0; j < 4; ++j) dot[i][j] += av[i] * bv[j];
      }
      __syncthreads();
    }
#pragma unroll
    for (int i = 0; i < 4; ++i) {
      float sn = sqv[b * N + n0 + ty * 4 + i];
#pragma unroll
      for (int j = 0; j < 4; ++j)
        dtile[ty * 4 + i][tx * 4 + j] = sn + sqv[b * N + m0 + tx * 4 + j] - 2.f * dot[i][j];
    }
    __syncthreads();
    if (tid < 64) {
      unsigned long long* lst = top[tid];
      for (int j = 0; j < 64; ++j) {
        unsigned u = __float_as_uint(dtile[tid][j]);
        u = (u & 0x80000000u) ? ~u : (u | 0x80000000u);
        unsigned long long key = ((unsigned long long)u << 32) | (unsigned)(m0 + j);
        if (key < lst[KNN]) {
          int p = KNN;
          while (p > 0 && lst[p - 1] > key) {
            lst[p] = lst[p - 1];
            --p;
          }
          lst[p] = key;
        }
      }
    }
    __syncthreads();
  }
  if (tid < 64) {
    int n = n0 + tid;
    for (int k = 0; k < KNN; ++k)
      idxb[(b * N + n) * KNN + k] = (int)(top[tid][k + 1] & 0xFFFFFFFFull);
  }
}

// ---------------------------------------------------------------- edge conv (fused)
// e[k][o] = sum_c Wd[o,c]*nbr[k][c] + sum_c (Wc[o,c]-Wd[o,c])*cen[c]
// accumulates channel sum/sumsq (atomics) and writes max over k (raw) into
// the feats slice; finalize normalizes in place.
template <int C, int O>
__global__ __launch_bounds__(256) void edge_kernel(const float* __restrict__ h, int hstride,
                                                   const int* __restrict__ idxb,
                                                   const float* __restrict__ Wt,  // [2C][O]
                                                   float* __restrict__ cstats,    // [B*O*2]
                                                   float* __restrict__ featdst) { // feats col slice
  constexpr int KG = 256 / O;
  constexpr int KPG = KNN / KG;
  int bn = blockIdx.x;
  int b = bn >> 11;
  int tid = threadIdx.x;
  int o = tid % O;
  int kg = tid / O;

  __shared__ __align__(16) float nbr[KNN][C];
  __shared__ float cen[C];
  __shared__ int knn[KNN];
  __shared__ float red[3][KG][O];

  const float* hrow = h + (size_t)bn * hstride;
  if (tid < C) cen[tid] = hrow[tid];
  if (tid < KNN) knn[tid] = idxb[bn * KNN + tid];
  __syncthreads();
  for (int i = tid; i < KNN * C; i += 256) {
    int k = i / C, c = i - k * C;
    nbr[k][c] = h[(size_t)(b * N + knn[k]) * hstride + c];
  }
  __syncthreads();

  float ecen = 0.f;
  for (int c = 0; c < C; ++c)
    ecen += (Wt[(C + c) * O + o] - Wt[c * O + o]) * cen[c];

  float acc[KPG];
#pragma unroll
  for (int j = 0; j < KPG; ++j) acc[j] = ecen;

  if constexpr (C % 4 == 0) {
    for (int c = 0; c < C; c += 4) {
      float w0 = Wt[(c + 0) * O + o];
      float w1 = Wt[(c + 1) * O + o];
      float w2 = Wt[(c + 2) * O + o];
      float w3 = Wt[(c + 3) * O + o];
#pragma unroll
      for (int j = 0; j < KPG; ++j) {
        const float4 v = *reinterpret_cast<const float4*>(&nbr[kg * KPG + j][c]);
        acc[j] += w0 * v.x + w1 * v.y + w2 * v.z + w3 * v.w;
      }
    }
  } else {
    for (int c = 0; c < C; ++c) {
      float w = Wt[c * O + o];
#pragma unroll
      for (int j = 0; j < KPG; ++j) acc[j] += w * nbr[kg * KPG + j][c];
    }
  }

  float s = 0.f, ss = 0.f, mx = -3.4e38f;
#pragma unroll
  for (int j = 0; j < KPG; ++j) {
    float e = acc[j];
    s += e;
    ss += e * e;
    mx = fmaxf(mx, e);
  }

  if constexpr (KG > 1) {
    red[0][kg][o] = s;
    red[1][kg][o] = ss;
    red[2][kg][o] = mx;
    __syncthreads();
    if (kg == 0) {
#pragma unroll
      for (int g = 1; g < KG; ++g) {
        s += red[0][g][o];
        ss += red[1][g][o];
        mx = fmaxf(mx, red[2][g][o]);
      }
    }
  }
  if (kg == 0) {
    atomicAdd(&cstats[(b * O + o) * 2 + 0], s);
    atomicAdd(&cstats[(b * O + o) * 2 + 1], ss);
    featdst[(size_t)bn * FD + o] = mx;
  }
}

// in-place: featdst = lrelu((featdst - mean) * rsqrt(var + eps))
__global__ void finalize_kernel(const float* __restrict__ cstats,
                                float* __restrict__ featdst, int O) {
  int i = blockIdx.x * 256 + threadIdx.x;  // (b*N+n)*O + o
  int o = i % O;
  int bn = i / O;
  int b = bn >> 11;
  float s = cstats[(b * O + o) * 2 + 0];
  float ss = cstats[(b * O + o) * 2 + 1];
  constexpr float inv = 1.f / ((float)N * KNN);
  float m = s * inv;
  float v = fmaxf(ss * inv - m * m, 0.f);
  float* p = &featdst[(size_t)bn * FD + o];
  float e = (*p - m) * rsqrtf(v + EPS);
  *p = lrelu(e);
}

// ---------------------------------------------------------------- 480 -> 128 stage
__global__ __launch_bounds__(256) void fstage_kernel(const float* __restrict__ feats,
                                                     const float* __restrict__ Wht,  // [480][128]
                                                     float* __restrict__ fsum,
                                                     float* __restrict__ fss,
                                                     unsigned* __restrict__ fmaxu) {
  int blk = blockIdx.x;
  int b = blk >> 7;
  int n0 = (blk & 127) * 16;
  int tid = threadIdx.x;
  __shared__ float rows[16][FD];
  __shared__ float red[3][2][128];
  for (int i = tid; i < 16 * FD; i += 256) {
    int r = i / FD, c = i - r * FD;
    rows[r][c] = feats[(size_t)(b * N + n0 + r) * FD + c];
  }
  __syncthreads();
  int o = tid & 127, g = tid >> 7;
  float acc[8] = {};
  for (int c = 0; c < FD; ++c) {
    float w = Wht[c * 128 + o];
#pragma unroll
    for (int j = 0; j < 8; ++j) acc[j] += w * rows[g * 8 + j][c];
  }
  float s = 0.f, ss = 0.f, mx = -3.4e38f;
#pragma unroll
  for (int j = 0; j < 8; ++j) {
    float f = acc[j];
    s += f;
    ss += f * f;
    mx = fmaxf(mx, f);
  }
  red[0][g][o] = s;
  red[1][g][o] = ss;
  red[2][g][o] = mx;
  __syncthreads();
  if (g == 0) {
    s += red[0][1][o];
    ss += red[1][1][o];
    mx = fmaxf(mx, red[2][1][o]);
    atomicAdd(&fsum[b * 128 + o], s);
    atomicAdd(&fss[b * 128 + o], ss);
    unsigned u = __float_as_uint(mx);
    u = (u & 0x80000000u) ? ~u : (u | 0x80000000u);
    atomicMax(&fmaxu[b * 128 + o], u);
  }
}

// ---------------------------------------------------------------- head
__global__ __launch_bounds__(128) void head_kernel(const float* __restrict__ fsum,
                                                   const float* __restrict__ fss,
                                                   const unsigned* __restrict__ fmaxu,
                                                   const float* __restrict__ fc1w,
                                                   const float* __restrict__ fc1b,
                                                   const float* __restrict__ fc2w,
                                                   const float* __restrict__ fc2b,
                                                   void* __restrict__ out,
                                                   const int* __restrict__ flag) {
  int b = blockIdx.x, o = threadIdx.x;
  __shared__ float gs[128], t1[128], ys[128];
  constexpr float invN = 1.f / N;
  float m = fsum[b * 128 + o] * invN;
  float v = fmaxf(fss[b * 128 + o] * invN - m * m, 0.f);
  unsigned u = fmaxu[b * 128 + o];
  unsigned bits = (u & 0x80000000u) ? (u ^ 0x80000000u) : ~u;
  float fx = __uint_as_float(bits);
  gs[o] = lrelu((fx - m) * rsqrtf(v + EPS));
  __syncthreads();
  float a = fc1b[o];
  for (int c = 0; c < 128; ++c) a += fc1w[o * 128 + c] * gs[c];
  t1[o] = a;
  __syncthreads();
  float mm = 0.f;
  for (int c = 0; c < 128; ++c) mm += t1[c];
  mm *= (1.f / 128);
  float vv = 0.f;
  for (int c = 0; c < 128; ++c) {
    float d = t1[c] - mm;
    vv += d * d;
  }
  vv *= (1.f / 128);
  ys[o] = lrelu((a - mm) * rsqrtf(vv + EPS));
  __syncthreads();
  float r = fc2b[o];
  for (int c = 0; c < 128; ++c) r += fc2w[o * 128 + c] * ys[c];
  if (flag[0])
    ((float*)out)[b * 128 + o] = r;
  else
    ((bf16*)out)[b * 128 + o] = __float2bfloat16(r);
}

// ---------------------------------------------------------------- driver
template <int C, int O>
static void run_layer(const float* h, int hstride, float* featdst, const float* Wt,
                      float* cstats, float* sqv, int* idxb, hipStream_t stream) {
  sq_kernel<<<B * N / 256, 256, 0, stream>>>(h, hstride, C, sqv);
  knn_kernel<C><<<dim3(N / 64, B), 256, 0, stream>>>(h, hstride, sqv, idxb);
  edge_kernel<C, O><<<B * N, 256, 0, stream>>>(h, hstride, idxb, Wt, cstats, featdst);
  finalize_kernel<<<B * N * O / 256, 256, 0, stream>>>(cstats, featdst, O);
}

extern "C" void kernel_launch(void* const* d_in, const int* in_sizes, int n_in,
                              void* d_out, int out_size, void* d_ws, size_t ws_size,
                              hipStream_t stream) {
  const void* x = d_in[0];
  // d_in[1] = normals, unused (include_normals=False)
  const void* W0 = d_in[2];
  const void* W1 = d_in[3];
  const void* W2 = d_in[4];
  const void* W3 = d_in[5];
  const void* Wh = d_in[6];
  const void* fc1w = d_in[7];
  const void* fc1b = d_in[8];
  const void* fc2w = d_in[9];
  const void* fc2b = d_in[10];

  float* ws = (float*)d_ws;
  size_t off = 0;
  auto alloc = [&](size_t n) {
    float* p = ws + off;
    off += n;
    return p;
  };
  float* xf = alloc((size_t)B * N * 3);
  float* feats = alloc((size_t)B * N * FD);
  float* sqv = alloc((size_t)B * N);
  int* idxb = (int*)alloc((size_t)B * N * KNN);
  float* wt0 = alloc(32 * 6);
  float* wt1 = alloc(64 * 64);
  float* wt2 = alloc(128 * 128);
  float* wt3 = alloc(256 * 256);
  float* wht = alloc(480 * 128);
  float* f1w = alloc(128 * 128);
  float* f1b = alloc(128);
  float* f2w = alloc(128 * 128);
  float* f2b = alloc(128);
  int* flag = (int*)alloc(64);
  float* zstart = ws + off;  // everything below is zero-initialized per launch
  float* cs0 = alloc(B * 32 * 2);
  float* cs1 = alloc(B * 64 * 2);
  float* cs2 = alloc(B * 128 * 2);
  float* cs3 = alloc(B * 256 * 2);
  float* fsum = alloc(B * 128);
  float* fss = alloc(B * 128);
  unsigned* fmaxu = (unsigned*)alloc(B * 128);
  size_t zbytes = (size_t)((ws + off) - zstart) * sizeof(float);

  hipMemsetAsync(zstart, 0, zbytes, stream);
  sniff_kernel<<<1, 256, 0, stream>>>((const unsigned short*)x, B * N * 3, flag);
  convert_kernel<<<(B * N * 3 + 255) / 256, 256, 0, stream>>>(x, xf, B * N * 3, flag);
  transpose_w_kernel<<<1, 256, 0, stream>>>(W0, wt0, 32, 6, flag);
  transpose_w_kernel<<<16, 256, 0, stream>>>(W1, wt1, 64, 64, flag);
  transpose_w_kernel<<<64, 256, 0, stream>>>(W2, wt2, 128, 128, flag);
  transpose_w_kernel<<<256, 256, 0, stream>>>(W3, wt3, 256, 256, flag);
  transpose_w_kernel<<<240, 256, 0, stream>>>(Wh, wht, 128, 480, flag);
  convert_kernel<<<64, 256, 0, stream>>>(fc1w, f1w, 128 * 128, flag);
  convert_kernel<<<1, 128, 0, stream>>>(fc1b, f1b, 128, flag);
  convert_kernel<<<64, 256, 0, stream>>>(fc2w, f2w, 128 * 128, flag);
  convert_kernel<<<1, 128, 0, stream>>>(fc2b, f2b, 128, flag);

  run_layer<3, 32>(xf, 3, feats + 0, wt0, cs0, sqv, idxb, stream);
  run_layer<32, 64>(feats + 0, FD, feats + 32, wt1, cs1, sqv, idxb, stream);
  run_layer<64, 128>(feats + 32, FD, feats + 96, wt2, cs2, sqv, idxb, stream);
  run_layer<128, 256>(feats + 96, FD, feats + 224, wt3, cs3, sqv, idxb, stream);

  fstage_kernel<<<B * 128, 256, 0, stream>>>(feats, wht, fsum, fss, fmaxu);
  head_kernel<<<B, 128, 0, stream>>>(fsum, fss, fmaxu, f1w, f1b, f2w, f2b, d_out, flag);
}

// Round 4
// 1807.600 us; speedup vs baseline: 4.9901x; 4.9901x over previous
//
#include <hip/hip_runtime.h>
#include <hip/hip_bf16.h>
#include <cstdint>

using bf16 = __hip_bfloat16;

static constexpr int B = 2;
static constexpr int N = 2048;
static constexpr int KNN = 32;
static constexpr int FD = 480;
static constexpr float EPS = 1e-5f;
static constexpr float SLOPE = 0.2f;

__device__ __forceinline__ float lrelu(float x) { return x >= 0.f ? x : SLOPE * x; }

// ---------------------------------------------------------------- dtype sniff
__global__ void sniff_kernel(const unsigned short* __restrict__ xr, int nelem,
                             int* __restrict__ flag) {
  __shared__ float red[256];
  float mx = 0.f;
  for (int i = threadIdx.x; i < nelem; i += 256) {
    float v = __uint_as_float(((unsigned)xr[i]) << 16);
    v = fabsf(v);
    if (!(v < 1e30f)) v = 1e30f;  // NaN/inf -> huge
    mx = fmaxf(mx, v);
  }
  red[threadIdx.x] = mx;
  __syncthreads();
  for (int s = 128; s > 0; s >>= 1) {
    if (threadIdx.x < s) red[threadIdx.x] = fmaxf(red[threadIdx.x], red[threadIdx.x + s]);
    __syncthreads();
  }
  if (threadIdx.x == 0) flag[0] = (red[0] > 1e3f) ? 1 : 0;
}

__device__ __forceinline__ float load_in(const void* p, int i, int isf32) {
  return isf32 ? ((const float*)p)[i] : __bfloat162float(((const bf16*)p)[i]);
}

// ---------------------------------------------------------------- prep
__global__ void convert_kernel(const void* __restrict__ x, float* __restrict__ xf, int n,
                               const int* __restrict__ flag) {
  int i = blockIdx.x * 256 + threadIdx.x;
  int isf = flag[0];
  if (i < n) xf[i] = load_in(x, i, isf);
}

// W [O][IC] -> Wt [IC][O] (fp32)
__global__ void transpose_w_kernel(const void* __restrict__ W, float* __restrict__ Wt,
                                   int O, int IC, const int* __restrict__ flag) {
  int i = blockIdx.x * 256 + threadIdx.x;
  int isf = flag[0];
  if (i < O * IC) {
    int o = i / IC, c = i - o * IC;
    Wt[c * O + o] = load_in(W, i, isf);
  }
}

// ---------------------------------------------------------------- knn
__global__ void sq_kernel(const float* __restrict__ h, int stride, int C,
                          float* __restrict__ sqv) {
  int i = blockIdx.x * 256 + threadIdx.x;  // b*N + n
  const float* r = h + (size_t)i * stride;
  float s = 0.f;
  for (int c = 0; c < C; ++c) s += r[c] * r[c];
  sqv[i] = s;
}

template <int C>
__global__ __launch_bounds__(256) void dist_kernel(const float* __restrict__ h, int hstride,
                                                   const float* __restrict__ sqv,
                                                   float* __restrict__ dist) {
  constexpr int CW = 32;
  __shared__ float As[64][CW + 1];
  __shared__ float Bs[64][CW + 1];
  int b = blockIdx.z;
  int n0 = blockIdx.y * 64, m0 = blockIdx.x * 64;
  int tid = threadIdx.x;
  int tx = tid & 15, ty = tid >> 4;
  float dot[4][4] = {};
  for (int cc = 0; cc < C; cc += CW) {
    for (int i = tid; i < 64 * CW; i += 256) {
      int r = i >> 5, c = i & 31;
      int gc = cc + c;
      float av = 0.f, bv = 0.f;
      if (gc < C) {
        av = h[(size_t)(b * N + n0 + r) * hstride + gc];
        bv = h[(size_t)(b * N + m0 + r) * hstride + gc];
      }
      As[r][c] = av;
      Bs[r][c] = bv;
    }
    __syncthreads();
    for (int c = 0; c < CW; ++c) {
      float av[4], bv[4];
#pragma unroll
      for (int i = 0; i < 4; ++i) av[i] = As[ty * 4 + i][c];
#pragma unroll
      for (int j = 0; j < 4; ++j) bv[j] = Bs[tx * 4 + j][c];
#pragma unroll
      for (int i = 0; i < 4; ++i)
#pragma unroll
        for (int j = 0; j < 4; ++j) dot[i][j] += av[i] * bv[j];
    }
    __syncthreads();
  }
#pragma unroll
  for (int i = 0; i < 4; ++i) {
    int nn = n0 + ty * 4 + i;
    float sn = sqv[b * N + nn];
    float4 w;
    w.x = sn + sqv[b * N + m0 + tx * 4 + 0] - 2.f * dot[i][0];
    w.y = sn + sqv[b * N + m0 + tx * 4 + 1] - 2.f * dot[i][1];
    w.z = sn + sqv[b * N + m0 + tx * 4 + 2] - 2.f * dot[i][2];
    w.w = sn + sqv[b * N + m0 + tx * 4 + 3] - 2.f * dot[i][3];
    *reinterpret_cast<float4*>(&dist[(size_t)(b * N + nn) * N + m0 + tx * 4]) = w;
  }
}

__device__ __forceinline__ unsigned long long wave_min_u64(unsigned long long v) {
#pragma unroll
  for (int m = 1; m < 64; m <<= 1) {
    unsigned lo = (unsigned)v;
    unsigned hi = (unsigned)(v >> 32);
    unsigned olo = (unsigned)__shfl_xor((int)lo, m, 64);
    unsigned ohi = (unsigned)__shfl_xor((int)hi, m, 64);
    unsigned long long ov = ((unsigned long long)ohi << 32) | olo;
    if (ov < v) v = ov;
  }
  return v;
}

// One wave per row: lane caches 32 keys in registers, 33 extract-min rounds.
// Key = (ordered_dist_bits << 32) | col  -> exact top_k order (dist asc, idx asc).
__global__ __launch_bounds__(256) void select_kernel(const float* __restrict__ dist,
                                                     int* __restrict__ idxb) {
  int row = blockIdx.x * 4 + (threadIdx.x >> 6);  // b*N + n
  int lane = threadIdx.x & 63;
  const float* drow = dist + (size_t)row * N;
  unsigned long long key[32];
#pragma unroll
  for (int j = 0; j < 32; ++j) {
    int m = j * 64 + lane;
    unsigned u = __float_as_uint(drow[m]);
    u = (u & 0x80000000u) ? ~u : (u | 0x80000000u);
    key[j] = ((unsigned long long)u << 32) | (unsigned)m;
  }
  unsigned long long lmin = key[0];
#pragma unroll
  for (int j = 1; j < 32; ++j) lmin = key[j] < lmin ? key[j] : lmin;
  unsigned saved = 0;
  for (int it = 0; it <= KNN; ++it) {
    unsigned long long gmin = wave_min_u64(lmin);
    if (it > 0 && lane == it - 1) saved = (unsigned)(gmin & 0xFFFFFFFFull);
    if (lmin == gmin) {  // unique keys -> exactly one winner lane
#pragma unroll
      for (int j = 0; j < 32; ++j)
        if (key[j] == gmin) key[j] = ~0ull;
      lmin = key[0];
#pragma unroll
      for (int j = 1; j < 32; ++j) lmin = key[j] < lmin ? key[j] : lmin;
    }
  }
  if (lane < KNN) idxb[row * KNN + lane] = (int)saved;
}

// ---------------------------------------------------------------- edge conv (fused)
template <int C, int O>
__global__ __launch_bounds__(256) void edge_kernel(const float* __restrict__ h, int hstride,
                                                   const int* __restrict__ idxb,
                                                   const float* __restrict__ Wt,  // [2C][O]
                                                   float* __restrict__ cstats,    // [B*O*2]
                                                   float* __restrict__ featdst) { // feats col slice
  constexpr int KG = 256 / O;
  constexpr int KPG = KNN / KG;
  int bn = blockIdx.x;
  int b = bn >> 11;
  int tid = threadIdx.x;
  int o = tid % O;
  int kg = tid / O;

  __shared__ __align__(16) float nbr[KNN][C];
  __shared__ float cen[C];
  __shared__ int knn[KNN];
  __shared__ float red[3][KG][O];

  const float* hrow = h + (size_t)bn * hstride;
  if (tid < C) cen[tid] = hrow[tid];
  if (tid < KNN) knn[tid] = idxb[bn * KNN + tid];
  __syncthreads();
  for (int i = tid; i < KNN * C; i += 256) {
    int k = i / C, c = i - k * C;
    nbr[k][c] = h[(size_t)(b * N + knn[k]) * hstride + c];
  }
  __syncthreads();

  float ecen = 0.f;
  for (int c = 0; c < C; ++c)
    ecen += (Wt[(C + c) * O + o] - Wt[c * O + o]) * cen[c];

  float acc[KPG];
#pragma unroll
  for (int j = 0; j < KPG; ++j) acc[j] = ecen;

  if constexpr (C % 4 == 0) {
    for (int c = 0; c < C; c += 4) {
      float w0 = Wt[(c + 0) * O + o];
      float w1 = Wt[(c + 1) * O + o];
      float w2 = Wt[(c + 2) * O + o];
      float w3 = Wt[(c + 3) * O + o];
#pragma unroll
      for (int j = 0; j < KPG; ++j) {
        const float4 v = *reinterpret_cast<const float4*>(&nbr[kg * KPG + j][c]);
        acc[j] += w0 * v.x + w1 * v.y + w2 * v.z + w3 * v.w;
      }
    }
  } else {
    for (int c = 0; c < C; ++c) {
      float w = Wt[c * O + o];
#pragma unroll
      for (int j = 0; j < KPG; ++j) acc[j] += w * nbr[kg * KPG + j][c];
    }
  }

  float s = 0.f, ss = 0.f, mx = -3.4e38f;
#pragma unroll
  for (int j = 0; j < KPG; ++j) {
    float e = acc[j];
    s += e;
    ss += e * e;
    mx = fmaxf(mx, e);
  }

  if constexpr (KG > 1) {
    red[0][kg][o] = s;
    red[1][kg][o] = ss;
    red[2][kg][o] = mx;
    __syncthreads();
    if (kg == 0) {
#pragma unroll
      for (int g = 1; g < KG; ++g) {
        s += red[0][g][o];
        ss += red[1][g][o];
        mx = fmaxf(mx, red[2][g][o]);
      }
    }
  }
  if (kg == 0) {
    atomicAdd(&cstats[(b * O + o) * 2 + 0], s);
    atomicAdd(&cstats[(b * O + o) * 2 + 1], ss);
    featdst[(size_t)bn * FD + o] = mx;
  }
}

// in-place: featdst = lrelu((featdst - mean) * rsqrt(var + eps))
__global__ void finalize_kernel(const float* __restrict__ cstats,
                                float* __restrict__ featdst, int O) {
  int i = blockIdx.x * 256 + threadIdx.x;  // (b*N+n)*O + o
  int o = i % O;
  int bn = i / O;
  int b = bn >> 11;
  float s = cstats[(b * O + o) * 2 + 0];
  float ss = cstats[(b * O + o) * 2 + 1];
  constexpr float inv = 1.f / ((float)N * KNN);
  float m = s * inv;
  float v = fmaxf(ss * inv - m * m, 0.f);
  float* p = &featdst[(size_t)bn * FD + o];
  float e = (*p - m) * rsqrtf(v + EPS);
  *p = lrelu(e);
}

// ---------------------------------------------------------------- 480 -> 128 stage
__global__ __launch_bounds__(256) void fstage_kernel(const float* __restrict__ feats,
                                                     const float* __restrict__ Wht,  // [480][128]
                                                     float* __restrict__ fsum,
                                                     float* __restrict__ fss,
                                                     unsigned* __restrict__ fmaxu) {
  int blk = blockIdx.x;
  int b = blk >> 7;
  int n0 = (blk & 127) * 16;
  int tid = threadIdx.x;
  __shared__ float rows[16][FD];
  __shared__ float red[3][2][128];
  for (int i = tid; i < 16 * FD; i += 256) {
    int r = i / FD, c = i - r * FD;
    rows[r][c] = feats[(size_t)(b * N + n0 + r) * FD + c];
  }
  __syncthreads();
  int o = tid & 127, g = tid >> 7;
  float acc[8] = {};
  for (int c = 0; c < FD; ++c) {
    float w = Wht[c * 128 + o];
#pragma unroll
    for (int j = 0; j < 8; ++j) acc[j] += w * rows[g * 8 + j][c];
  }
  float s = 0.f, ss = 0.f, mx = -3.4e38f;
#pragma unroll
  for (int j = 0; j < 8; ++j) {
    float f = acc[j];
    s += f;
    ss += f * f;
    mx = fmaxf(mx, f);
  }
  red[0][g][o] = s;
  red[1][g][o] = ss;
  red[2][g][o] = mx;
  __syncthreads();
  if (g == 0) {
    s += red[0][1][o];
    ss += red[1][1][o];
    mx = fmaxf(mx, red[2][1][o]);
    atomicAdd(&fsum[b * 128 + o], s);
    atomicAdd(&fss[b * 128 + o], ss);
    unsigned u = __float_as_uint(mx);
    u = (u & 0x80000000u) ? ~u : (u | 0x80000000u);
    atomicMax(&fmaxu[b * 128 + o], u);
  }
}

// ---------------------------------------------------------------- head
__global__ __launch_bounds__(128) void head_kernel(const float* __restrict__ fsum,
                                                   const float* __restrict__ fss,
                                                   const unsigned* __restrict__ fmaxu,
                                                   const float* __restrict__ fc1w,
                                                   const float* __restrict__ fc1b,
                                                   const float* __restrict__ fc2w,
                                                   const float* __restrict__ fc2b,
                                                   void* __restrict__ out,
                                                   const int* __restrict__ flag) {
  int b = blockIdx.x, o = threadIdx.x;
  __shared__ float gs[128], t1[128], ys[128];
  constexpr float invN = 1.f / N;
  float m = fsum[b * 128 + o] * invN;
  float v = fmaxf(fss[b * 128 + o] * invN - m * m, 0.f);
  unsigned u = fmaxu[b * 128 + o];
  unsigned bits = (u & 0x80000000u) ? (u ^ 0x80000000u) : ~u;
  float fx = __uint_as_float(bits);
  gs[o] = lrelu((fx - m) * rsqrtf(v + EPS));
  __syncthreads();
  float a = fc1b[o];
  for (int c = 0; c < 128; ++c) a += fc1w[o * 128 + c] * gs[c];
  t1[o] = a;
  __syncthreads();
  float mm = 0.f;
  for (int c = 0; c < 128; ++c) mm += t1[c];
  mm *= (1.f / 128);
  float vv = 0.f;
  for (int c = 0; c < 128; ++c) {
    float d = t1[c] - mm;
    vv += d * d;
  }
  vv *= (1.f / 128);
  ys[o] = lrelu((a - mm) * rsqrtf(vv + EPS));
  __syncthreads();
  float r = fc2b[o];
  for (int c = 0; c < 128; ++c) r += fc2w[o * 128 + c] * ys[c];
  if (flag[0])
    ((float*)out)[b * 128 + o] = r;
  else
    ((bf16*)out)[b * 128 + o] = __float2bfloat16(r);
}

// ---------------------------------------------------------------- driver
template <int C, int O>
static void run_layer(const float* h, int hstride, float* featdst, const float* Wt,
                      float* cstats, float* sqv, float* dist, int* idxb,
                      hipStream_t stream) {
  sq_kernel<<<B * N / 256, 256, 0, stream>>>(h, hstride, C, sqv);
  dist_kernel<C><<<dim3(N / 64, N / 64, B), 256, 0, stream>>>(h, hstride, sqv, dist);
  select_kernel<<<B * N / 4, 256, 0, stream>>>(dist, idxb);
  edge_kernel<C, O><<<B * N, 256, 0, stream>>>(h, hstride, idxb, Wt, cstats, featdst);
  finalize_kernel<<<B * N * O / 256, 256, 0, stream>>>(cstats, featdst, O);
}

extern "C" void kernel_launch(void* const* d_in, const int* in_sizes, int n_in,
                              void* d_out, int out_size, void* d_ws, size_t ws_size,
                              hipStream_t stream) {
  const void* x = d_in[0];
  // d_in[1] = normals, unused (include_normals=False)
  const void* W0 = d_in[2];
  const void* W1 = d_in[3];
  const void* W2 = d_in[4];
  const void* W3 = d_in[5];
  const void* Wh = d_in[6];
  const void* fc1w = d_in[7];
  const void* fc1b = d_in[8];
  const void* fc2w = d_in[9];
  const void* fc2b = d_in[10];

  float* ws = (float*)d_ws;
  size_t off = 0;
  auto alloc = [&](size_t n) {
    float* p = ws + off;
    off += n;
    return p;
  };
  float* xf = alloc((size_t)B * N * 3);
  float* feats = alloc((size_t)B * N * FD);
  float* dist = alloc((size_t)B * N * N);
  float* sqv = alloc((size_t)B * N);
  int* idxb = (int*)alloc((size_t)B * N * KNN);
  float* wt0 = alloc(32 * 6);
  float* wt1 = alloc(64 * 64);
  float* wt2 = alloc(128 * 128);
  float* wt3 = alloc(256 * 256);
  float* wht = alloc(480 * 128);
  float* f1w = alloc(128 * 128);
  float* f1b = alloc(128);
  float* f2w = alloc(128 * 128);
  float* f2b = alloc(128);
  int* flag = (int*)alloc(64);
  float* zstart = ws + off;  // everything below is zero-initialized per launch
  float* cs0 = alloc(B * 32 * 2);
  float* cs1 = alloc(B * 64 * 2);
  float* cs2 = alloc(B * 128 * 2);
  float* cs3 = alloc(B * 256 * 2);
  float* fsum = alloc(B * 128);
  float* fss = alloc(B * 128);
  unsigned* fmaxu = (unsigned*)alloc(B * 128);
  size_t zbytes = (size_t)((ws + off) - zstart) * sizeof(float);

  hipMemsetAsync(zstart, 0, zbytes, stream);
  sniff_kernel<<<1, 256, 0, stream>>>((const unsigned short*)x, B * N * 3, flag);
  convert_kernel<<<(B * N * 3 + 255) / 256, 256, 0, stream>>>(x, xf, B * N * 3, flag);
  transpose_w_kernel<<<1, 256, 0, stream>>>(W0, wt0, 32, 6, flag);
  transpose_w_kernel<<<16, 256, 0, stream>>>(W1, wt1, 64, 64, flag);
  transpose_w_kernel<<<64, 256, 0, stream>>>(W2, wt2, 128, 128, flag);
  transpose_w_kernel<<<256, 256, 0, stream>>>(W3, wt3, 256, 256, flag);
  transpose_w_kernel<<<240, 256, 0, stream>>>(Wh, wht, 128, 480, flag);
  convert_kernel<<<64, 256, 0, stream>>>(fc1w, f1w, 128 * 128, flag);
  convert_kernel<<<1, 128, 0, stream>>>(fc1b, f1b, 128, flag);
  convert_kernel<<<64, 256, 0, stream>>>(fc2w, f2w, 128 * 128, flag);
  convert_kernel<<<1, 128, 0, stream>>>(fc2b, f2b, 128, flag);

  run_layer<3, 32>(xf, 3, feats + 0, wt0, cs0, sqv, dist, idxb, stream);
  run_layer<32, 64>(feats + 0, FD, feats + 32, wt1, cs1, sqv, dist, idxb, stream);
  run_layer<64, 128>(feats + 32, FD, feats + 96, wt2, cs2, sqv, dist, idxb, stream);
  run_layer<128, 256>(feats + 96, FD, feats + 224, wt3, cs3, sqv, dist, idxb, stream);

  fstage_kernel<<<B * 128, 256, 0, stream>>>(feats, wht, fsum, fss, fmaxu);
  head_kernel<<<B, 128, 0, stream>>>(fsum, fss, fmaxu, f1w, f1b, f2w, f2b, d_out, flag);
}